// Round 1
// baseline (390.977 us; speedup 1.0000x reference)
//
#include <hip/hip_runtime.h>
#include <math.h>

#define B_TOTAL   1048576
#define N_IMG     4096
#define EMB       64

// ws layout: ws[0..63] = u = w_value @ w_out ; ws[64] = c = b_value@w_out + b_out ; ws[65] = b_out
__global__ void prep_kernel(const float* __restrict__ w_value,
                            const float* __restrict__ b_value,
                            const float* __restrict__ w_out,
                            const float* __restrict__ b_out,
                            float* __restrict__ ws) {
    int e = threadIdx.x;              // 0..63
    float acc = 0.f;
    for (int h = 0; h < EMB; ++h) acc += w_value[e * EMB + h] * w_out[h];
    ws[e] = acc;
    if (e == 0) {
        float c = 0.f;
        for (int h = 0; h < EMB; ++h) c += b_value[h] * w_out[h];
        ws[EMB]     = c + b_out[0];
        ws[EMB + 1] = b_out[0];
    }
}

__global__ __launch_bounds__(256) void seg_attn_kernel(
    const float* __restrict__ emb,
    const int*   __restrict__ ids,
    const float* __restrict__ w_attn,
    const float* __restrict__ ws,
    float*       __restrict__ out) {
    const int n   = blockIdx.x;       // image / segment id
    const int tid = threadIdx.x;

    __shared__ int   s_range[2];
    __shared__ float s_m[16], s_d[16], s_num[16];
    __shared__ float s_r;

    // segment bounds via binary search on sorted ids
    if (tid < 2) {
        int key = n + tid;
        int lo = 0, hi = B_TOTAL;
        while (lo < hi) {
            int mid = (lo + hi) >> 1;
            if (ids[mid] < key) lo = mid + 1; else hi = mid;
        }
        s_range[tid] = lo;
    }
    __syncthreads();
    const int start = s_range[0], end = s_range[1];

    const int lane = tid & 15;        // lane within 16-lane row-group
    const int grp  = tid >> 4;        // 16 groups per block

    const float4 wa = reinterpret_cast<const float4*>(w_attn)[lane];
    const float4 uu = reinterpret_cast<const float4*>(ws)[lane];
    const float  c    = ws[EMB];
    const float  bout = ws[EMB + 1];

    // online softmax state (replicated across the 16 lanes of a group)
    float m = -INFINITY, d = 0.f, num = 0.f;

    for (int r = start + grp; r < end; r += 16) {
        const float4 e4 = reinterpret_cast<const float4*>(emb + (size_t)r * EMB)[lane];
        float s = e4.x * wa.x + e4.y * wa.y + e4.z * wa.z + e4.w * wa.w;
        float v = e4.x * uu.x + e4.y * uu.y + e4.z * uu.z + e4.w * uu.w;
        // butterfly reduce over the 16-lane group: all lanes get full sums
        for (int off = 8; off; off >>= 1) {
            s += __shfl_xor(s, off, 16);
            v += __shfl_xor(v, off, 16);
        }
        float mn    = fmaxf(m, s);
        float scale = __expf(m - mn);  // m=-inf first iter -> scale=0
        float e_    = __expf(s - mn);
        d   = d * scale + e_;
        num = num * scale + e_ * v;
        m   = mn;
    }

    if (lane == 0) { s_m[grp] = m; s_d[grp] = d; s_num[grp] = num; }
    __syncthreads();

    if (tid == 0) {
        float M = -INFINITY;
        for (int g = 0; g < 16; ++g) M = fmaxf(M, s_m[g]);
        float D = 0.f, NUM = 0.f;
        if (M > -INFINITY) {
            for (int g = 0; g < 16; ++g) {
                float sc = __expf(s_m[g] - M);   // empty group: exp(-inf)=0
                D   += s_d[g]   * sc;
                NUM += s_num[g] * sc;
            }
        }
        float r = (end > start) ? (NUM / D + c) : bout;  // empty segment: pooled=0 -> b_out
        s_r = r;
        out[(size_t)B_TOTAL + n]          = r;          // r_images
        out[(size_t)B_TOTAL + N_IMG + n]  = (float)n;   // unique_ids
    }
    __syncthreads();

    // broadcast r to this segment's contiguous reflection slice
    const float r = s_r;
    for (int i = start + tid; i < end; i += 256) out[i] = r;
}

extern "C" void kernel_launch(void* const* d_in, const int* in_sizes, int n_in,
                              void* d_out, int out_size, void* d_ws, size_t ws_size,
                              hipStream_t stream) {
    const float* emb     = (const float*)d_in[0];
    const int*   ids     = (const int*)  d_in[1];
    const float* w_attn  = (const float*)d_in[2];
    // d_in[3] = b_attn: cancels inside the segment softmax, unused
    const float* w_value = (const float*)d_in[4];
    const float* b_value = (const float*)d_in[5];
    const float* w_out   = (const float*)d_in[6];
    const float* b_out   = (const float*)d_in[7];
    float* out = (float*)d_out;
    float* ws  = (float*)d_ws;

    prep_kernel<<<1, 64, 0, stream>>>(w_value, b_value, w_out, b_out, ws);
    seg_attn_kernel<<<N_IMG, 256, 0, stream>>>(emb, ids, w_attn, ws, out);
}

// Round 2
// 380.499 us; speedup vs baseline: 1.0275x; 1.0275x over previous
//
#include <hip/hip_runtime.h>
#include <math.h>

#define B_TOTAL 1048576
#define N_IMG   4096
#define EMB     64
#define CHUNK   1024                 // rows per block in partial pass
#define NBLK    (B_TOTAL / CHUNK)    // 1024 blocks

// ws layout (floats):
//   [0      .. 4095]  d[n]    (softmax denominators, atomically accumulated)
//   [4096   .. 8191]  num[n]  (weighted-value numerators)
//   [8192   .. 8255]  u[e] = sum_h w_value[e][h]*w_out[h]
//   [8256]            c    = b_value@w_out + b_out
//   [8257]            bout = b_out

// raw ds_swizzle xor-butterfly within a 16-lane group (masks 1,2,4,8 never
// cross the 16-lane boundary; pattern = (xor<<10)|0x1F per cdna4_isa.md)
#define SWZ_ADD(x, imm) \
    (x) += __int_as_float(__builtin_amdgcn_ds_swizzle(__float_as_int(x), (imm)))

__global__ void init_kernel(const float* __restrict__ w_value,
                            const float* __restrict__ b_value,
                            const float* __restrict__ w_out,
                            const float* __restrict__ b_out,
                            float* __restrict__ ws) {
    int t = blockIdx.x * blockDim.x + threadIdx.x;
    if (t < 2 * N_IMG) {
        ws[t] = 0.f;                      // zero d[] and num[] (ws is poisoned)
    } else if (t < 2 * N_IMG + EMB) {
        int e = t - 2 * N_IMG;
        float acc = 0.f;
        for (int h = 0; h < EMB; ++h) acc += w_value[e * EMB + h] * w_out[h];
        ws[2 * N_IMG + e] = acc;          // u[e]
        if (e == 0) {
            float c = 0.f;
            for (int h = 0; h < EMB; ++h) c += b_value[h] * w_out[h];
            ws[2 * N_IMG + EMB]     = c + b_out[0];   // c
            ws[2 * N_IMG + EMB + 1] = b_out[0];       // bout
        }
    }
}

__global__ __launch_bounds__(256) void partial_kernel(
    const float* __restrict__ emb,
    const int*   __restrict__ ids,
    const float* __restrict__ w_attn,
    const float* __restrict__ ws,
    float*       __restrict__ d_acc,     // ws[0..4095]
    float*       __restrict__ num_acc) { // ws[4096..8191]
    const int tid  = threadIdx.x;
    const int lane = tid & 15;           // lane within 16-lane group
    const int grp  = tid >> 4;           // 16 groups per block
    const int base = blockIdx.x * CHUNK;

    const float4 wa = reinterpret_cast<const float4*>(w_attn)[lane];
    const float4 uu = reinterpret_cast<const float4*>(ws + 2 * N_IMG)[lane];

    int   r       = base + grp;
    int   cur_id  = ids[r];              // group-uniform (broadcast load)
    float acc_d   = 0.f;                 // replicated across the 16 lanes
    float acc_num = 0.f;                 // per-lane PARTIAL of numerator

    auto flush = [&]() {
        float nsum = acc_num;            // reduce the per-lane partials now
        SWZ_ADD(nsum, 0x041F);           // xor 1
        SWZ_ADD(nsum, 0x081F);           // xor 2
        SWZ_ADD(nsum, 0x101F);           // xor 4
        SWZ_ADD(nsum, 0x201F);           // xor 8
        if (lane == 0) {
            atomicAdd(&d_acc[cur_id],   acc_d);
            atomicAdd(&num_acc[cur_id], nsum);
        }
    };

    #pragma unroll 4
    for (int i = 0; i < CHUNK / 16; ++i, r += 16) {
        const float4 e4 = reinterpret_cast<const float4*>(emb + (size_t)r * EMB)[lane];
        const int rid = ids[r];          // group-uniform; non-decreasing over i
        float s = e4.x * wa.x + e4.y * wa.y + e4.z * wa.z + e4.w * wa.w;
        float v = e4.x * uu.x + e4.y * uu.y + e4.z * uu.z + e4.w * uu.w;
        // full score: butterfly over the 16-lane group (s only; v stays partial)
        SWZ_ADD(s, 0x041F);
        SWZ_ADD(s, 0x081F);
        SWZ_ADD(s, 0x101F);
        SWZ_ADD(s, 0x201F);
        if (rid != cur_id) {             // group-uniform branch, rare (~5/64)
            flush();
            acc_d = 0.f; acc_num = 0.f; cur_id = rid;
        }
        const float e = __expf(s);       // max-free: |s| <~ 4, exact-safe in fp32
        acc_d   += e;
        acc_num += e * v;
    }
    flush();
}

__global__ void finalize_kernel(const float* __restrict__ ws,
                                float* __restrict__ out) {
    int n = blockIdx.x * blockDim.x + threadIdx.x;
    if (n >= N_IMG) return;
    const float d    = ws[n];
    const float num  = ws[N_IMG + n];
    const float c    = ws[2 * N_IMG + EMB];
    const float bout = ws[2 * N_IMG + EMB + 1];
    const float rv   = (d != 0.f) ? (num / d + c) : bout;  // empty seg -> b_out
    out[(size_t)B_TOTAL + n]         = rv;        // r_images
    out[(size_t)B_TOTAL + N_IMG + n] = (float)n;  // unique_ids
}

__global__ __launch_bounds__(256) void scatter_kernel(
    const int*   __restrict__ ids,
    const float* __restrict__ r_img,   // = out + B_TOTAL (16 KB, L2-resident)
    float*       __restrict__ out) {
    int i = blockIdx.x * blockDim.x + threadIdx.x;   // 4 rows per thread
    int4 id4 = reinterpret_cast<const int4*>(ids)[i];
    float4 o;
    o.x = r_img[id4.x]; o.y = r_img[id4.y];
    o.z = r_img[id4.z]; o.w = r_img[id4.w];
    reinterpret_cast<float4*>(out)[i] = o;
}

extern "C" void kernel_launch(void* const* d_in, const int* in_sizes, int n_in,
                              void* d_out, int out_size, void* d_ws, size_t ws_size,
                              hipStream_t stream) {
    const float* emb     = (const float*)d_in[0];
    const int*   ids     = (const int*)  d_in[1];
    const float* w_attn  = (const float*)d_in[2];
    // d_in[3] = b_attn: cancels inside the segment softmax, unused
    const float* w_value = (const float*)d_in[4];
    const float* b_value = (const float*)d_in[5];
    const float* w_out   = (const float*)d_in[6];
    const float* b_out   = (const float*)d_in[7];
    float* out = (float*)d_out;
    float* ws  = (float*)d_ws;

    init_kernel<<<(2 * N_IMG + EMB + 255) / 256, 256, 0, stream>>>(
        w_value, b_value, w_out, b_out, ws);
    partial_kernel<<<NBLK, 256, 0, stream>>>(
        emb, ids, w_attn, ws, ws, ws + N_IMG);
    finalize_kernel<<<(N_IMG + 255) / 256, 256, 0, stream>>>(ws, out);
    scatter_kernel<<<B_TOTAL / (256 * 4), 256, 0, stream>>>(
        ids, out + B_TOTAL, out);
}